// Round 2
// baseline (188.649 us; speedup 1.0000x reference)
//
#include <hip/hip_runtime.h>

typedef unsigned int u32;
typedef unsigned long long u64;
typedef unsigned char u8;
typedef unsigned short u16;

// Marching-tets tables (from reference)
__constant__ int c_tt[16][6] = {
  {-1,-1,-1,-1,-1,-1},{1,0,2,-1,-1,-1},{4,0,3,-1,-1,-1},{1,4,2,1,3,4},
  {3,1,5,-1,-1,-1},{2,3,0,2,5,3},{1,4,0,1,5,4},{4,2,5,-1,-1,-1},
  {4,5,2,-1,-1,-1},{4,1,0,4,5,1},{3,2,0,3,5,2},{1,3,5,-1,-1,-1},
  {4,1,2,4,3,1},{3,0,4,-1,-1,-1},{2,0,1,-1,-1,-1},{-1,-1,-1,-1,-1,-1}};
__constant__ int c_ntri[16] = {0,1,1,2,1,2,2,1,1,2,2,1,2,1,1,0};
// Kuhn split: corner indices per tet; corner j has offset coff[j] (offs order of reference)
__constant__ int c_kuhn[6][4] = {{0,1,3,7},{0,2,3,7},{0,1,5,7},{0,2,6,7},{0,4,5,7},{0,4,6,7}};
__constant__ int c_e0[6] = {0,0,0,1,1,2};
__constant__ int c_e1[6] = {1,2,3,2,3,3};

// ---------------- scan helpers (wave64) ----------------
__device__ __forceinline__ u32 wave_incscan_u32(u32 v) {
  int lane = threadIdx.x & 63;
#pragma unroll
  for (int d = 1; d < 64; d <<= 1) {
    u32 n = __shfl_up(v, (unsigned)d, 64);
    if (lane >= d) v += n;
  }
  return v;
}
__device__ __forceinline__ u64 wave_incscan_u64(u64 v) {
  int lane = threadIdx.x & 63;
#pragma unroll
  for (int d = 1; d < 64; d <<= 1) {
    u32 lo = __shfl_up((u32)v, (unsigned)d, 64);
    u32 hi = __shfl_up((u32)(v >> 32), (unsigned)d, 64);
    u64 n = ((u64)hi << 32) | (u64)lo;
    if (lane >= d) v += n;
  }
  return v;
}
__device__ __forceinline__ u32 block_exscan_u32(u32 v, u32* wsums, u32* total) {
  int tid = threadIdx.x, lane = tid & 63, w = tid >> 6, nw = blockDim.x >> 6;
  u32 inc = wave_incscan_u32(v);
  if (lane == 63) wsums[w] = inc;
  __syncthreads();
  u32 woff = 0, tot = 0;
  for (int i = 0; i < nw; i++) { u32 s = wsums[i]; tot += s; if (i < w) woff += s; }
  __syncthreads();
  if (total) *total = tot;
  return woff + inc - v;
}
__device__ __forceinline__ u64 block_exscan_u64(u64 v, u64* wsums, u64* total) {
  int tid = threadIdx.x, lane = tid & 63, w = tid >> 6, nw = blockDim.x >> 6;
  u64 inc = wave_incscan_u64(v);
  if (lane == 63) wsums[w] = inc;
  __syncthreads();
  u64 woff = 0, tot = 0;
  for (int i = 0; i < nw; i++) { u64 s = wsums[i]; tot += s; if (i < w) woff += s; }
  __syncthreads();
  if (total) *total = tot;
  return woff + inc - v;
}

// ---------------- kernels ----------------
// 1) per-vertex crossing mask (7 outgoing edges in sorted-Delta order), 4 verts/thread,
//    packed 4 masks into one u32 store; per-block edge count -> bsumV
__global__ void k_vmask(const float* __restrict__ sdf, u32* __restrict__ vmask4,
                        u32* __restrict__ bsum, int NV, int R, int R1, int R1sq) {
  __shared__ u32 ws[8];
  int tid = threadIdx.x;
  int v0 = blockIdx.x * 2048 + tid * 4;
  u32 pack = 0, cnt = 0;
#pragma unroll
  for (int i = 0; i < 4; i++) {
    int v = v0 + i;
    u32 m = 0;
    if (v < NV) {
      int z = v % R1, tq = v / R1, y = tq % R1, x = tq / R1;
      bool o = sdf[v] > 0.0f;
      bool bx = x < R, by = y < R, bz = z < R;
      if (bz && (sdf[v + 1] > 0.0f) != o) m |= 1;
      if (by && (sdf[v + R1] > 0.0f) != o) m |= 2;
      if (by && bz && (sdf[v + R1 + 1] > 0.0f) != o) m |= 4;
      if (bx && (sdf[v + R1sq] > 0.0f) != o) m |= 8;
      if (bx && bz && (sdf[v + R1sq + 1] > 0.0f) != o) m |= 16;
      if (bx && by && (sdf[v + R1sq + R1] > 0.0f) != o) m |= 32;
      if (bx && by && bz && (sdf[v + R1sq + R1 + 1] > 0.0f) != o) m |= 64;
    }
    pack |= m << (8 * i);
    cnt += __popc(m);
  }
  vmask4[v0 >> 2] = pack;
  u32 tot;
  block_exscan_u32(cnt, ws, &tot);
  if (tid == 0) bsum[blockIdx.x] = tot;
}

// 2) per-cube corner-occupancy byte (tet vids are arithmetic; no tets[] read),
//    2 cubes/thread; packed (m1|m2<<16) block sums widened to u64
__global__ void k_occ8(const float* __restrict__ sdf, u8* __restrict__ occ8,
                       u64* __restrict__ bsumT, int Tc, int R, int R1, int R1sq) {
  __shared__ u32 ws[4];
  int tid = threadIdx.x;
  int c0 = blockIdx.x * 512 + tid * 2;
  int coff[8] = {0, R1sq, R1, R1sq + R1, 1, R1sq + 1, R1 + 1, R1sq + R1 + 1};
  u32 packed = 0;
  u16 two = 0;
#pragma unroll
  for (int i = 0; i < 2; i++) {
    int c = c0 + i;
    if (c < Tc) {
      int z = c % R, tq = c / R, y = tq % R, x = tq / R;
      int v000 = (x * R1 + y) * R1 + z;
      u32 b = 0;
#pragma unroll
      for (int j = 0; j < 8; j++) b |= (sdf[v000 + coff[j]] > 0.0f ? 1u : 0u) << j;
      two |= (u16)(b << (8 * i));
#pragma unroll
      for (int k = 0; k < 6; k++) {
        int code = ((b >> c_kuhn[k][0]) & 1) | (((b >> c_kuhn[k][1]) & 1) << 1) |
                   (((b >> c_kuhn[k][2]) & 1) << 2) | (((b >> c_kuhn[k][3]) & 1) << 3);
        int n = c_ntri[code];
        packed += (n == 1 ? 1u : 0u) + (n == 2 ? (1u << 16) : 0u);
      }
    }
  }
  if (c0 < Tc) *(u16*)(occ8 + c0) = two;
  u32 tot;
  block_exscan_u32(packed, ws, &tot);
  if (tid == 0) bsumT[blockIdx.x] = (u64)(tot & 0xffffu) | ((u64)(tot >> 16) << 32);
}

// 3) fused single-block aux scans: bsumV -> boffV + hdr[0]=E; bsumT -> boffT + hdr[1]=F1,hdr[2]=F2
__global__ void k_scan(const u32* __restrict__ bsumV, u32* __restrict__ boffV, int nv,
                       const u64* __restrict__ bsumT, u64* __restrict__ boffT, int nt,
                       u32* __restrict__ hdr) {
  __shared__ u32 ws32[16];
  __shared__ u64 ws64[16];
  u32 carry = 0;
  for (int base = 0; base < nv; base += blockDim.x) {
    int i = base + threadIdx.x;
    u32 v = (i < nv) ? bsumV[i] : 0;
    u32 tot;
    u32 ex = block_exscan_u32(v, ws32, &tot);
    if (i < nv) boffV[i] = carry + ex;
    carry += tot;
  }
  if (threadIdx.x == 0) hdr[0] = carry;
  u64 carry2 = 0;
  for (int base = 0; base < nt; base += blockDim.x) {
    int i = base + threadIdx.x;
    u64 v = (i < nt) ? bsumT[i] : 0;
    u64 tot;
    u64 ex = block_exscan_u64(v, ws64, &tot);
    if (i < nt) boffT[i] = carry2 + ex;
    carry2 += tot;
  }
  if (threadIdx.x == 0) { hdr[1] = (u32)carry2; hdr[2] = (u32)(carry2 >> 32); }
}

// 4) vertex writer: recompute block exscan, store vbase, emit interpolated crossing verts.
//    Deformed positions computed on the fly (verts + sdefs*tanh(deform)).
__global__ void k_vertsout(const float* __restrict__ verts, const float* __restrict__ sdf,
                           const float* __restrict__ deform, const u32* __restrict__ vmask4,
                           const u32* __restrict__ boffV, u32* __restrict__ vbase,
                           float* __restrict__ out, int NV, int R1, int R1sq, float sdefs) {
  __shared__ u32 ws[8];
  int tid = threadIdx.x;
  int v0 = blockIdx.x * 2048 + tid * 4;
  u32 pack = vmask4[v0 >> 2];
  u32 cnt = __popc(pack);
  u32 ex = block_exscan_u32(cnt, ws, nullptr);
  u32 base = boffV[blockIdx.x] + ex;
  // store vbase for the 4 vertices (16B aligned; buffer padded)
  uint4 vb;
  u32 run = base;
  vb.x = run; run += __popc(pack & 0xffu);
  vb.y = run; run += __popc((pack >> 8) & 0xffu);
  vb.z = run; run += __popc((pack >> 16) & 0xffu);
  vb.w = run;
  *(uint4*)(vbase + v0) = vb;
  int deltas[7] = {1, R1, R1 + 1, R1sq, R1sq + 1, R1sq + R1, R1sq + R1 + 1};
  u32 r = base;
#pragma unroll
  for (int i = 0; i < 4; i++) {
    int v = v0 + i;
    u32 m = (pack >> (8 * i)) & 0x7fu;
    if (!m) continue;
    float sa = sdf[v];
    float pa0 = verts[3 * v + 0] + sdefs * tanhf(deform[3 * v + 0]);
    float pa1 = verts[3 * v + 1] + sdefs * tanhf(deform[3 * v + 1]);
    float pa2 = verts[3 * v + 2] + sdefs * tanhf(deform[3 * v + 2]);
#pragma unroll
    for (int k = 0; k < 7; k++) {
      if ((m >> k) & 1) {
        int b = v + deltas[k];
        float sb = sdf[b];
        float den = sa - sb;  // opposite signs -> no cancellation
        float w0 = -sb / den, w1 = sa / den;
        float pb0 = verts[3 * b + 0] + sdefs * tanhf(deform[3 * b + 0]);
        float pb1 = verts[3 * b + 1] + sdefs * tanhf(deform[3 * b + 1]);
        float pb2 = verts[3 * b + 2] + sdefs * tanhf(deform[3 * b + 2]);
        out[3 * r + 0] = pa0 * w0 + pb0 * w1;
        out[3 * r + 1] = pa1 * w0 + pb1 * w1;
        out[3 * r + 2] = pa2 * w0 + pb2 * w1;
        r++;
      }
    }
  }
}

// 5) face writer: recompute block exscan of (m1,m2), emit faces + uv_idx. Tet vids arithmetic.
__global__ void k_facesout(const u8* __restrict__ occ8, const u32* __restrict__ vbase,
                           const u32* __restrict__ vmask4, const u64* __restrict__ boffT,
                           const u32* __restrict__ hdr, float* __restrict__ out,
                           int Tc, int R, int R1, int R1sq, long long uvtot) {
  __shared__ u32 ws[4];
  int tid = threadIdx.x;
  int c0 = blockIdx.x * 512 + tid * 2;
  u16 two = (c0 < Tc) ? *(const u16*)(occ8 + c0) : (u16)0;
  int codes[12];
  u32 packed = 0;
#pragma unroll
  for (int i = 0; i < 2; i++) {
    u32 b = (two >> (8 * i)) & 0xffu;
#pragma unroll
    for (int k = 0; k < 6; k++) {
      int code = ((b >> c_kuhn[k][0]) & 1) | (((b >> c_kuhn[k][1]) & 1) << 1) |
                 (((b >> c_kuhn[k][2]) & 1) << 2) | (((b >> c_kuhn[k][3]) & 1) << 3);
      codes[6 * i + k] = code;
      int n = c_ntri[code];
      packed += (n == 1 ? 1u : 0u) + (n == 2 ? (1u << 16) : 0u);
    }
  }
  u32 ex = block_exscan_u32(packed, ws, nullptr);
  if (c0 >= Tc) return;
  u64 bo = boffT[blockIdx.x];
  u32 s1 = (u32)bo + (ex & 0xffffu);
  u32 s2 = (u32)(bo >> 32) + (ex >> 16);
  u32 E = hdr[0], F1 = hdr[1], F2 = hdr[2];
  u32 F = F1 + 2u * F2;
  size_t fb = (size_t)3 * E;
  size_t ub = fb + (size_t)3 * F + (size_t)uvtot;
  int coff[8] = {0, R1sq, R1, R1sq + R1, 1, R1sq + 1, R1 + 1, R1sq + R1 + 1};
#pragma unroll
  for (int i = 0; i < 2; i++) {
    int c = c0 + i;
    int z = c % R, tq = c / R, y = tq % R, x = tq / R;
    int v000 = (x * R1 + y) * R1 + z;
    int t6 = 6 * c;
    for (int k = 0; k < 6; k++) {
      int code = codes[6 * i + k];
      int n = c_ntri[code];
      if (n == 0) continue;
      for (int tri = 0; tri < n; tri++) {
        u32 row = (n == 1) ? s1 : (F1 + 2u * s2 + (u32)tri);
#pragma unroll
        for (int j = 0; j < 3; j++) {
          int slot = c_tt[code][3 * tri + j];
          int ci = c_kuhn[k][c_e0[slot]], cj = c_kuhn[k][c_e1[slot]];
          int oa = coff[ci], ob = coff[cj];
          int lo = oa < ob ? oa : ob;
          int d = oa < ob ? ob - oa : oa - ob;
          int va = v000 + lo;
          int dx = d >= R1sq ? 1 : 0; d -= dx * R1sq;
          int dy = d >= R1 ? 1 : 0;   d -= dy * R1;     // d now dz
          int kb = (dx << 2) + (dy << 1) + d - 1;
          u32 vm = (vmask4[va >> 2] >> ((va & 3) * 8)) & 0xffu;
          u32 fidx = vbase[va] + __popc(vm & ((1u << kb) - 1u));
          out[fb + 3 * row + j] = (float)fidx;
        }
        int g4 = 4 * (t6 + k);
        out[ub + 3 * row + 0] = (float)g4;
        out[ub + 3 * row + 1] = (float)(g4 + tri + 1);
        out[ub + 3 * row + 2] = (float)(g4 + tri + 2);
      }
      if (n == 1) s1++; else s2++;
    }
  }
}

// 6) uvs section (data-independent values at device-computed offset 3E+3F)
__global__ void k_uvs(float* __restrict__ out, const u32* __restrict__ hdr, int NU, double inv) {
  int i = blockIdx.x * blockDim.x + threadIdx.x;
  int ncell = NU * NU;
  if (i >= ncell) return;
  u32 E = hdr[0], F = hdr[1] + 2u * hdr[2];
  size_t base = (size_t)3 * E + (size_t)3 * F + (size_t)8 * i;
  int row = i / NU, col = i % NU;
  float x = (float)((double)col * inv);
  float y = (float)((double)row * inv);
  float pad = (float)(0.9 * inv);
  float xp = x + pad, yp = y + pad;
  out[base + 0] = x;  out[base + 1] = y;
  out[base + 2] = xp; out[base + 3] = y;
  out[base + 4] = xp; out[base + 5] = yp;
  out[base + 6] = x;  out[base + 7] = yp;
}

extern "C" void kernel_launch(void* const* d_in, const int* in_sizes, int n_in,
                              void* d_out, int out_size, void* d_ws, size_t ws_size,
                              hipStream_t stream) {
  const float* verts = (const float*)d_in[0];
  const float* sdf = (const float*)d_in[1];
  const float* deform = (const float*)d_in[2];
  int NV = in_sizes[0] / 3;
  int T = in_sizes[3] / 4;
  int R = 1;
  while ((long long)(R + 1) * (R + 1) * (R + 1) < (long long)NV) R++;
  int R1 = R + 1, R1sq = R1 * R1;
  int Tc = T / 6;  // cubes
  int NU = 1;
  while ((long long)NU * NU < (long long)T) NU++;  // N = ceil(sqrt((2T+1)//2)) = ceil(sqrt(T))
  long long UVTOT = 8LL * NU * NU;
  int Bv = (NV + 2047) / 2048;          // 512 thr x 4 verts
  int Bt = (Tc + 511) / 512;            // 256 thr x 2 cubes (12 tets)
  int NVpad = Bv * 2048;

  // workspace carve (u64 first for alignment)
  char* w = (char*)d_ws;
  u64* bsumT = (u64*)w; w += (size_t)Bt * 8;
  u64* boffT = (u64*)w; w += (size_t)Bt * 8;
  u32* vbase = (u32*)w; w += (size_t)NVpad * 4;
  u32* vmask4 = (u32*)w; w += (size_t)NVpad;       // NVpad bytes as u32[NVpad/4]
  u32* bsumV = (u32*)w; w += (size_t)Bv * 4;
  u32* boffV = (u32*)w; w += (size_t)Bv * 4;
  u32* hdr = (u32*)w;   w += 16;
  u8* occ8 = (u8*)w;    w += (size_t)Tc + 2;

  float sdefs = 2.0f / (float)(R * 2);  // 1/64 exact
  double inv = 1.0 / (double)NU;
  float* outf = (float*)d_out;

  k_vmask<<<dim3(Bv), dim3(512), 0, stream>>>(sdf, vmask4, bsumV, NV, R, R1, R1sq);
  k_occ8<<<dim3(Bt), dim3(256), 0, stream>>>(sdf, occ8, bsumT, Tc, R, R1, R1sq);
  k_scan<<<dim3(1), dim3(1024), 0, stream>>>(bsumV, boffV, Bv, bsumT, boffT, Bt, hdr);
  k_vertsout<<<dim3(Bv), dim3(512), 0, stream>>>(verts, sdf, deform, vmask4, boffV, vbase,
                                                 outf, NV, R1, R1sq, sdefs);
  k_facesout<<<dim3(Bt), dim3(256), 0, stream>>>(occ8, vbase, vmask4, boffT, hdr, outf,
                                                 Tc, R, R1, R1sq, UVTOT);
  k_uvs<<<dim3((NU * NU + 255) / 256), dim3(256), 0, stream>>>(outf, hdr, NU, inv);
}

// Round 3
// 160.401 us; speedup vs baseline: 1.1761x; 1.1761x over previous
//
#include <hip/hip_runtime.h>

typedef unsigned int u32;
typedef unsigned long long u64;
typedef unsigned char u8;

// Marching-tets tables (from reference)
__constant__ int c_tt[16][6] = {
  {-1,-1,-1,-1,-1,-1},{1,0,2,-1,-1,-1},{4,0,3,-1,-1,-1},{1,4,2,1,3,4},
  {3,1,5,-1,-1,-1},{2,3,0,2,5,3},{1,4,0,1,5,4},{4,2,5,-1,-1,-1},
  {4,5,2,-1,-1,-1},{4,1,0,4,5,1},{3,2,0,3,5,2},{1,3,5,-1,-1,-1},
  {4,1,2,4,3,1},{3,0,4,-1,-1,-1},{2,0,1,-1,-1,-1},{-1,-1,-1,-1,-1,-1}};
__constant__ int c_ntri[16] = {0,1,1,2,1,2,2,1,1,2,2,1,2,1,1,0};
__constant__ int c_kuhn[6][4] = {{0,1,3,7},{0,2,3,7},{0,1,5,7},{0,2,6,7},{0,4,5,7},{0,4,6,7}};
__constant__ int c_e0[6] = {0,0,0,1,1,2};
__constant__ int c_e1[6] = {1,2,3,2,3,3};

// ---------------- scan helpers (wave64) ----------------
__device__ __forceinline__ u32 wave_incscan_u32(u32 v) {
  int lane = threadIdx.x & 63;
#pragma unroll
  for (int d = 1; d < 64; d <<= 1) {
    u32 n = __shfl_up(v, (unsigned)d, 64);
    if (lane >= d) v += n;
  }
  return v;
}
__device__ __forceinline__ u64 wave_incscan_u64(u64 v) {
  int lane = threadIdx.x & 63;
#pragma unroll
  for (int d = 1; d < 64; d <<= 1) {
    u32 lo = __shfl_up((u32)v, (unsigned)d, 64);
    u32 hi = __shfl_up((u32)(v >> 32), (unsigned)d, 64);
    u64 n = ((u64)hi << 32) | (u64)lo;
    if (lane >= d) v += n;
  }
  return v;
}
__device__ __forceinline__ u32 block_exscan_u32(u32 v, u32* wsums, u32* total) {
  int tid = threadIdx.x, lane = tid & 63, w = tid >> 6, nw = blockDim.x >> 6;
  u32 inc = wave_incscan_u32(v);
  if (lane == 63) wsums[w] = inc;
  __syncthreads();
  u32 woff = 0, tot = 0;
  for (int i = 0; i < nw; i++) { u32 s = wsums[i]; tot += s; if (i < w) woff += s; }
  __syncthreads();
  if (total) *total = tot;
  return woff + inc - v;
}
__device__ __forceinline__ u64 block_exscan_u64(u64 v, u64* wsums, u64* total) {
  int tid = threadIdx.x, lane = tid & 63, w = tid >> 6, nw = blockDim.x >> 6;
  u64 inc = wave_incscan_u64(v);
  if (lane == 63) wsums[w] = inc;
  __syncthreads();
  u64 woff = 0, tot = 0;
  for (int i = 0; i < nw; i++) { u64 s = wsums[i]; tot += s; if (i < w) woff += s; }
  __syncthreads();
  if (total) *total = tot;
  return woff + inc - v;
}

// ---------------- Kernel A: vmask (vertex blocks) + tcode (tet blocks) + block sums ----------------
__global__ __launch_bounds__(256) void kA(const float* __restrict__ sdf, u8* __restrict__ vmask,
                                          u8* __restrict__ tcode, u32* __restrict__ bsumV,
                                          u32* __restrict__ bsumT, int NV, int T, int nvb,
                                          int R, int R1, int R1sq) {
  __shared__ u32 ws[4];
  int tid = threadIdx.x, bid = blockIdx.x;
  if (bid < nvb) {
    int v = bid * 256 + tid;
    u32 m = 0;
    if (v < NV) {
      int z = v % R1, tq = v / R1, y = tq % R1, x = tq / R1;
      bool o = sdf[v] > 0.0f;
      bool bx = x < R, by = y < R, bz = z < R;
      if (bz && (sdf[v + 1] > 0.0f) != o) m |= 1;                        // (0,0,1)
      if (by && (sdf[v + R1] > 0.0f) != o) m |= 2;                       // (0,1,0)
      if (by && bz && (sdf[v + R1 + 1] > 0.0f) != o) m |= 4;             // (0,1,1)
      if (bx && (sdf[v + R1sq] > 0.0f) != o) m |= 8;                     // (1,0,0)
      if (bx && bz && (sdf[v + R1sq + 1] > 0.0f) != o) m |= 16;          // (1,0,1)
      if (bx && by && (sdf[v + R1sq + R1] > 0.0f) != o) m |= 32;         // (1,1,0)
      if (bx && by && bz && (sdf[v + R1sq + R1 + 1] > 0.0f) != o) m |= 64; // (1,1,1)
      vmask[v] = (u8)m;
    }
    u32 tot;
    block_exscan_u32(__popc(m), ws, &tot);
    if (tid == 0) bsumV[bid] = tot;
  } else {
    int t = (bid - nvb) * 256 + tid;
    u32 packed = 0;
    if (t < T) {
      int c = t / 6, k = t - 6 * c;
      int z = c % R, tq = c / R, y = tq % R, x = tq / R;
      int v000 = (x * R1 + y) * R1 + z;
      int coff[8] = {0, R1sq, R1, R1sq + R1, 1, R1sq + 1, R1 + 1, R1sq + R1 + 1};
      int code = 0;
#pragma unroll
      for (int j = 0; j < 4; j++)
        code |= (sdf[v000 + coff[c_kuhn[k][j]]] > 0.0f ? 1 : 0) << j;
      tcode[t] = (u8)code;
      int n = c_ntri[code];
      packed = (n == 1 ? 1u : 0u) | (n == 2 ? (1u << 16) : 0u);
    }
    u32 tot;
    block_exscan_u32(packed, ws, &tot);
    if (tid == 0) bsumT[bid - nvb] = tot;
  }
}

// ---------------- Kernel C: two independent aux scans (block 0: vertices, block 1: tets) ----------------
__global__ __launch_bounds__(1024) void kC(const u32* __restrict__ bsumV, u32* __restrict__ boffV,
                                           int nvb, const u32* __restrict__ bsumT,
                                           u64* __restrict__ boffT, int ntb, u32* __restrict__ hdr) {
  if (blockIdx.x == 0) {
    __shared__ u32 ws32[16];
    u32 carry = 0;
    for (int base = 0; base < nvb; base += 1024) {
      int i = base + threadIdx.x;
      u32 v = (i < nvb) ? bsumV[i] : 0;
      u32 tot;
      u32 ex = block_exscan_u32(v, ws32, &tot);
      if (i < nvb) boffV[i] = carry + ex;
      carry += tot;
    }
    if (threadIdx.x == 0) hdr[0] = carry;               // E
  } else {
    __shared__ u64 ws64[16];
    u64 carry = 0;
    for (int base = 0; base < ntb; base += 1024) {
      int i = base + threadIdx.x;
      u32 p = (i < ntb) ? bsumT[i] : 0;
      u64 v = (u64)(p & 0xffffu) | ((u64)(p >> 16) << 32);
      u64 tot;
      u64 ex = block_exscan_u64(v, ws64, &tot);
      if (i < ntb) boffT[i] = carry + ex;
      carry += tot;
    }
    if (threadIdx.x == 0) { hdr[1] = (u32)carry; hdr[2] = (u32)(carry >> 32); } // F1, F2
  }
}

// ---------------- Kernel D1: vertex writer (+vpack) blocks, then uv-writer blocks ----------------
__global__ __launch_bounds__(256) void kD1(const float* __restrict__ verts, const float* __restrict__ sdf,
                                           const float* __restrict__ deform, const u8* __restrict__ vmask,
                                           const u32* __restrict__ boffV, u32* __restrict__ vpack,
                                           const u32* __restrict__ hdr, float* __restrict__ out,
                                           int NV, int nvb, int R1, int R1sq, float sdefs,
                                           int NU, double inv) {
  int tid = threadIdx.x, bid = blockIdx.x;
  if (bid < nvb) {
    __shared__ u32 ws[4];
    int v = bid * 256 + tid;
    u32 m = (v < NV) ? (u32)vmask[v] : 0;
    u32 ex = block_exscan_u32(__popc(m), ws, nullptr);
    if (v >= NV) return;
    u32 base = boffV[bid] + ex;
    vpack[v] = (base << 7) | m;          // base < 2^24, mask 7 bits
    if (!m) return;
    int deltas[7] = {1, R1, R1 + 1, R1sq, R1sq + 1, R1sq + R1, R1sq + R1 + 1};
    float sa = sdf[v];
    float pa0 = verts[3 * v + 0] + sdefs * tanhf(deform[3 * v + 0]);
    float pa1 = verts[3 * v + 1] + sdefs * tanhf(deform[3 * v + 1]);
    float pa2 = verts[3 * v + 2] + sdefs * tanhf(deform[3 * v + 2]);
    u32 r = base;
#pragma unroll
    for (int k = 0; k < 7; k++) {
      if ((m >> k) & 1) {
        int b = v + deltas[k];
        float sb = sdf[b];
        float den = sa - sb;             // opposite signs -> no cancellation
        float w0 = -sb / den, w1 = sa / den;
        float pb0 = verts[3 * b + 0] + sdefs * tanhf(deform[3 * b + 0]);
        float pb1 = verts[3 * b + 1] + sdefs * tanhf(deform[3 * b + 1]);
        float pb2 = verts[3 * b + 2] + sdefs * tanhf(deform[3 * b + 2]);
        out[3 * r + 0] = pa0 * w0 + pb0 * w1;
        out[3 * r + 1] = pa1 * w0 + pb1 * w1;
        out[3 * r + 2] = pa2 * w0 + pb2 * w1;
        r++;
      }
    }
  } else {
    int i = (bid - nvb) * 256 + tid;
    if (i >= NU * NU) return;
    u32 E = hdr[0], F = hdr[1] + 2u * hdr[2];
    size_t base = (size_t)3 * E + (size_t)3 * F + (size_t)8 * (u32)i;
    int row = i / NU, col = i % NU;
    float x = (float)((double)col * inv);
    float y = (float)((double)row * inv);
    float pad = (float)(0.9 * inv);
    float xp = x + pad, yp = y + pad;
    out[base + 0] = x;  out[base + 1] = y;
    out[base + 2] = xp; out[base + 3] = y;
    out[base + 4] = xp; out[base + 5] = yp;
    out[base + 6] = x;  out[base + 7] = yp;
  }
}

// ---------------- Kernel D2: face + uv_idx writer, 1 tet/thread ----------------
__global__ __launch_bounds__(256) void kD2(const u8* __restrict__ tcode, const u32* __restrict__ vpack,
                                           const u64* __restrict__ boffT, const u32* __restrict__ hdr,
                                           float* __restrict__ out, int T, int R, int R1, int R1sq,
                                           long long uvtot) {
  __shared__ u32 ws[4];
  int tid = threadIdx.x, bid = blockIdx.x;
  int t = bid * 256 + tid;
  int code = (t < T) ? (int)tcode[t] : 0;
  int n = c_ntri[code];
  u32 packed = (n == 1 ? 1u : 0u) | (n == 2 ? (1u << 16) : 0u);
  u32 ex = block_exscan_u32(packed, ws, nullptr);
  if (t >= T || n == 0) return;
  u64 bo = boffT[bid];
  u32 s1 = (u32)bo + (ex & 0xffffu);
  u32 s2 = (u32)(bo >> 32) + (ex >> 16);
  u32 E = hdr[0], F1 = hdr[1], F2 = hdr[2];
  u32 F = F1 + 2u * F2;
  size_t fb = (size_t)3 * E;
  size_t ub = fb + (size_t)3 * F + (size_t)uvtot;
  int c = t / 6, k = t - 6 * c;
  int z = c % R, tq = c / R, y = tq % R, x = tq / R;
  int v000 = (x * R1 + y) * R1 + z;
  int coff[8] = {0, R1sq, R1, R1sq + R1, 1, R1sq + 1, R1 + 1, R1sq + R1 + 1};
  int g4 = 4 * t;
  for (int tri = 0; tri < n; tri++) {
    u32 row = (n == 1) ? s1 : (F1 + 2u * s2 + (u32)tri);
#pragma unroll
    for (int j = 0; j < 3; j++) {
      int slot = c_tt[code][3 * tri + j];
      int ci = c_kuhn[k][c_e0[slot]], cj = c_kuhn[k][c_e1[slot]];
      int oa = coff[ci], ob = coff[cj];
      int lo = oa < ob ? oa : ob;
      int d = oa < ob ? ob - oa : oa - ob;
      int va = v000 + lo;
      int dx = d >= R1sq ? 1 : 0; d -= dx * R1sq;
      int dy = d >= R1 ? 1 : 0;   d -= dy * R1;     // d now dz in {0,1}
      int kb = (dx << 2) + (dy << 1) + d - 1;       // slot in sorted-Delta order
      u32 pv = vpack[va];
      u32 fidx = (pv >> 7) + __popc(pv & 0x7fu & ((1u << kb) - 1u));
      out[fb + 3 * row + j] = (float)fidx;
    }
    out[ub + 3 * row + 0] = (float)g4;
    out[ub + 3 * row + 1] = (float)(g4 + tri + 1);
    out[ub + 3 * row + 2] = (float)(g4 + tri + 2);
  }
}

extern "C" void kernel_launch(void* const* d_in, const int* in_sizes, int n_in,
                              void* d_out, int out_size, void* d_ws, size_t ws_size,
                              hipStream_t stream) {
  const float* verts = (const float*)d_in[0];
  const float* sdf = (const float*)d_in[1];
  const float* deform = (const float*)d_in[2];
  int NV = in_sizes[0] / 3;
  int T = in_sizes[3] / 4;
  int R = 1;
  while ((long long)(R + 1) * (R + 1) * (R + 1) < (long long)NV) R++;
  int R1 = R + 1, R1sq = R1 * R1;
  int NU = 1;
  while ((long long)NU * NU < (long long)T) NU++;   // N = ceil(sqrt((2T+1)//2)) = ceil(sqrt(T))
  long long UVTOT = 8LL * NU * NU;
  int nvb = (NV + 255) / 256;       // vertex blocks
  int ntb = (T + 255) / 256;        // tet blocks
  int nub = (NU * NU + 255) / 256;  // uv blocks

  // workspace carve (u64 first for alignment); ~4 MB total
  char* w = (char*)d_ws;
  u64* boffT = (u64*)w; w += (size_t)ntb * 8;
  u32* bsumV = (u32*)w; w += (size_t)nvb * 4;
  u32* boffV = (u32*)w; w += (size_t)nvb * 4;
  u32* bsumT = (u32*)w; w += (size_t)ntb * 4;
  u32* vpack = (u32*)w; w += (size_t)NV * 4;
  u32* hdr = (u32*)w;   w += 16;
  u8* vmask = (u8*)w;   w += (size_t)NV;
  u8* tcode = (u8*)w;   w += (size_t)T;

  float sdefs = 2.0f / (float)(R * 2);  // 1/64 exact
  double inv = 1.0 / (double)NU;
  float* outf = (float*)d_out;

  kA<<<dim3(nvb + ntb), dim3(256), 0, stream>>>(sdf, vmask, tcode, bsumV, bsumT, NV, T, nvb, R, R1, R1sq);
  kC<<<dim3(2), dim3(1024), 0, stream>>>(bsumV, boffV, nvb, bsumT, boffT, ntb, hdr);
  kD1<<<dim3(nvb + nub), dim3(256), 0, stream>>>(verts, sdf, deform, vmask, boffV, vpack, hdr, outf,
                                                 NV, nvb, R1, R1sq, sdefs, NU, inv);
  kD2<<<dim3(ntb), dim3(256), 0, stream>>>(tcode, vpack, boffT, hdr, outf, T, R, R1, R1sq, UVTOT);
}

// Round 4
// 149.949 us; speedup vs baseline: 1.2581x; 1.0697x over previous
//
#include <hip/hip_runtime.h>

typedef unsigned int u32;
typedef unsigned long long u64;
typedef unsigned char u8;

// Marching-tets tables (from reference)
__constant__ int c_tt[16][6] = {
  {-1,-1,-1,-1,-1,-1},{1,0,2,-1,-1,-1},{4,0,3,-1,-1,-1},{1,4,2,1,3,4},
  {3,1,5,-1,-1,-1},{2,3,0,2,5,3},{1,4,0,1,5,4},{4,2,5,-1,-1,-1},
  {4,5,2,-1,-1,-1},{4,1,0,4,5,1},{3,2,0,3,5,2},{1,3,5,-1,-1,-1},
  {4,1,2,4,3,1},{3,0,4,-1,-1,-1},{2,0,1,-1,-1,-1},{-1,-1,-1,-1,-1,-1}};
__constant__ int c_ntri[16] = {0,1,1,2,1,2,2,1,1,2,2,1,2,1,1,0};
__constant__ int c_kuhn[6][4] = {{0,1,3,7},{0,2,3,7},{0,1,5,7},{0,2,6,7},{0,4,5,7},{0,4,6,7}};
__constant__ int c_e0[6] = {0,0,0,1,1,2};
__constant__ int c_e1[6] = {1,2,3,2,3,3};

// ---------------- scan helpers (wave64) ----------------
__device__ __forceinline__ u32 wave_incscan_u32(u32 v) {
  int lane = threadIdx.x & 63;
#pragma unroll
  for (int d = 1; d < 64; d <<= 1) {
    u32 n = __shfl_up(v, (unsigned)d, 64);
    if (lane >= d) v += n;
  }
  return v;
}
__device__ __forceinline__ u64 wave_incscan_u64(u64 v) {
  int lane = threadIdx.x & 63;
#pragma unroll
  for (int d = 1; d < 64; d <<= 1) {
    u32 lo = __shfl_up((u32)v, (unsigned)d, 64);
    u32 hi = __shfl_up((u32)(v >> 32), (unsigned)d, 64);
    u64 n = ((u64)hi << 32) | (u64)lo;
    if (lane >= d) v += n;
  }
  return v;
}
__device__ __forceinline__ u32 block_exscan_u32(u32 v, u32* wsums, u32* total) {
  int tid = threadIdx.x, lane = tid & 63, w = tid >> 6, nw = blockDim.x >> 6;
  u32 inc = wave_incscan_u32(v);
  if (lane == 63) wsums[w] = inc;
  __syncthreads();
  u32 woff = 0, tot = 0;
  for (int i = 0; i < nw; i++) { u32 s = wsums[i]; tot += s; if (i < w) woff += s; }
  __syncthreads();
  if (total) *total = tot;
  return woff + inc - v;
}
__device__ __forceinline__ u64 block_exscan_u64(u64 v, u64* wsums, u64* total) {
  int tid = threadIdx.x, lane = tid & 63, w = tid >> 6, nw = blockDim.x >> 6;
  u64 inc = wave_incscan_u64(v);
  if (lane == 63) wsums[w] = inc;
  __syncthreads();
  u64 woff = 0, tot = 0;
  for (int i = 0; i < nw; i++) { u64 s = wsums[i]; tot += s; if (i < w) woff += s; }
  __syncthreads();
  if (total) *total = tot;
  return woff + inc - v;
}

// ---------------- Kernel A: lpack (vertex blocks) + tcode (tet blocks) + block sums ----------------
// lpack[v] = (block-local edge rank << 7) | 7-bit crossing mask  — no global dependency.
template <int CR>
__global__ __launch_bounds__(256) void kA(const float* __restrict__ sdf, u32* __restrict__ lpack,
                                          u8* __restrict__ tcode, u32* __restrict__ bsumV,
                                          u32* __restrict__ bsumT, int NV, int T, int nvb, int rr) {
  const int R = CR ? CR : rr;
  const int R1 = R + 1, R1sq = R1 * R1;
  __shared__ u32 ws[4];
  int tid = threadIdx.x, bid = blockIdx.x;
  if (bid < nvb) {
    int v = bid * 256 + tid;
    u32 m = 0;
    if (v < NV) {
      int z = v % R1, tq = v / R1, y = tq % R1, x = tq / R1;
      bool o = sdf[v] > 0.0f;
      bool bx = x < R, by = y < R, bz = z < R;
      if (bz && (sdf[v + 1] > 0.0f) != o) m |= 1;                          // (0,0,1)
      if (by && (sdf[v + R1] > 0.0f) != o) m |= 2;                         // (0,1,0)
      if (by && bz && (sdf[v + R1 + 1] > 0.0f) != o) m |= 4;               // (0,1,1)
      if (bx && (sdf[v + R1sq] > 0.0f) != o) m |= 8;                       // (1,0,0)
      if (bx && bz && (sdf[v + R1sq + 1] > 0.0f) != o) m |= 16;            // (1,0,1)
      if (bx && by && (sdf[v + R1sq + R1] > 0.0f) != o) m |= 32;           // (1,1,0)
      if (bx && by && bz && (sdf[v + R1sq + R1 + 1] > 0.0f) != o) m |= 64; // (1,1,1)
    }
    u32 tot;
    u32 ex = block_exscan_u32(__popc(m), ws, &tot);
    if (v < NV) lpack[v] = (ex << 7) | m;
    if (tid == 0) bsumV[bid] = tot;
  } else {
    int t = (bid - nvb) * 256 + tid;
    u32 packed = 0;
    if (t < T) {
      int c = t / 6, k = t - 6 * c;
      int z = c % R, tq = c / R, y = tq % R, x = tq / R;
      int v000 = (x * R1 + y) * R1 + z;
      int coff[8] = {0, R1sq, R1, R1sq + R1, 1, R1sq + 1, R1 + 1, R1sq + R1 + 1};
      int code = 0;
#pragma unroll
      for (int j = 0; j < 4; j++)
        code |= (sdf[v000 + coff[c_kuhn[k][j]]] > 0.0f ? 1 : 0) << j;
      tcode[t] = (u8)code;
      int n = c_ntri[code];
      packed = (n == 1 ? 1u : 0u) | (n == 2 ? (1u << 16) : 0u);
    }
    u32 tot;
    block_exscan_u32(packed, ws, &tot);
    if (tid == 0) bsumT[bid - nvb] = tot;
  }
}

// ---------------- Kernel C: two independent aux scans ----------------
__global__ __launch_bounds__(1024) void kC(const u32* __restrict__ bsumV, u32* __restrict__ boffV,
                                           int nvb, const u32* __restrict__ bsumT,
                                           u64* __restrict__ boffT, int ntb, u32* __restrict__ hdr) {
  if (blockIdx.x == 0) {
    __shared__ u32 ws32[16];
    u32 carry = 0;
    for (int base = 0; base < nvb; base += 1024) {
      int i = base + threadIdx.x;
      u32 v = (i < nvb) ? bsumV[i] : 0;
      u32 tot;
      u32 ex = block_exscan_u32(v, ws32, &tot);
      if (i < nvb) boffV[i] = carry + ex;
      carry += tot;
    }
    if (threadIdx.x == 0) hdr[0] = carry;               // E
  } else {
    __shared__ u64 ws64[16];
    u64 carry = 0;
    for (int base = 0; base < ntb; base += 1024) {
      int i = base + threadIdx.x;
      u32 p = (i < ntb) ? bsumT[i] : 0;
      u64 v = (u64)(p & 0xffffu) | ((u64)(p >> 16) << 32);
      u64 tot;
      u64 ex = block_exscan_u64(v, ws64, &tot);
      if (i < ntb) boffT[i] = carry + ex;
      carry += tot;
    }
    if (threadIdx.x == 0) { hdr[1] = (u32)carry; hdr[2] = (u32)(carry >> 32); } // F1, F2
  }
}

// ---------------- Kernel D: vertex writer | uv writer | face writer (by block range) ----------------
template <int CR, int CNU>
__global__ __launch_bounds__(256) void kD(const float* __restrict__ verts, const float* __restrict__ sdf,
                                          const float* __restrict__ deform, const u32* __restrict__ lpack,
                                          const u32* __restrict__ boffV, const u8* __restrict__ tcode,
                                          const u64* __restrict__ boffT, const u32* __restrict__ hdr,
                                          float* __restrict__ out, int NV, int T, int nvb, int nuvb,
                                          int rr, int nuu, float sdefs, double inv) {
  const int R = CR ? CR : rr;
  const int R1 = R + 1, R1sq = R1 * R1;
  const int NU = CNU ? CNU : nuu;
  int tid = threadIdx.x, bid = blockIdx.x;
  if (bid < nvb) {
    // ---- vertex writer: 1 vertex/thread, rank from lpack (no block scan) ----
    int v = bid * 256 + tid;
    if (v >= NV) return;
    u32 pv = lpack[v];
    u32 m = pv & 0x7fu;
    if (!m) return;
    u32 r = boffV[bid] + (pv >> 7);
    int deltas[7] = {1, R1, R1 + 1, R1sq, R1sq + 1, R1sq + R1, R1sq + R1 + 1};
    float sa = sdf[v];
    float pa0 = verts[3 * v + 0] + sdefs * tanhf(deform[3 * v + 0]);
    float pa1 = verts[3 * v + 1] + sdefs * tanhf(deform[3 * v + 1]);
    float pa2 = verts[3 * v + 2] + sdefs * tanhf(deform[3 * v + 2]);
#pragma unroll
    for (int k = 0; k < 7; k++) {
      if ((m >> k) & 1) {
        int b = v + deltas[k];
        float sb = sdf[b];
        float den = sa - sb;  // opposite signs -> no cancellation
        float w0 = -sb / den, w1 = sa / den;
        float pb0 = verts[3 * b + 0] + sdefs * tanhf(deform[3 * b + 0]);
        float pb1 = verts[3 * b + 1] + sdefs * tanhf(deform[3 * b + 1]);
        float pb2 = verts[3 * b + 2] + sdefs * tanhf(deform[3 * b + 2]);
        out[3 * r + 0] = pa0 * w0 + pb0 * w1;
        out[3 * r + 1] = pa1 * w0 + pb1 * w1;
        out[3 * r + 2] = pa2 * w0 + pb2 * w1;
        r++;
      }
    }
  } else if (bid < nvb + nuvb) {
    // ---- uv writer: one aligned float4 per thread, value = f(output float index) ----
    long long chunk = (long long)(bid - nvb) * 256 + tid;
    u32 E = hdr[0], F = hdr[1] + 2u * hdr[2];
    size_t A = (size_t)3 * E + (size_t)3 * F;     // uv section start (float index)
    u32 sh = (u32)(A & 3);
    size_t A4 = A - sh;
    long long total = 8LL * NU * NU;
    long long e0 = 4 * chunk - (long long)sh;
    if (e0 >= total) return;
    float padf = (float)(0.9 * inv);
    float vals[4];
    bool ok[4];
    bool all4 = true;
#pragma unroll
    for (int j = 0; j < 3 + 1; j++) {
      long long e = e0 + j;
      bool valid = (e >= 0) && (e < total);
      ok[j] = valid;
      all4 &= valid;
      float val = 0.0f;
      if (valid) {
        u32 cell = (u32)(e >> 3);
        int comp = (int)(e & 7);
        u32 row = cell / (u32)NU, col = cell - row * (u32)NU;
        float b = (comp & 1) ? (float)((double)row * inv) : (float)((double)col * inv);
        bool addp = (comp == 2) | (comp == 4) | (comp == 5) | (comp == 7);
        val = addp ? b + padf : b;
      }
      vals[j] = val;
    }
    size_t basef = A4 + 4 * (size_t)chunk;
    if (all4) {
      *(float4*)(out + basef) = make_float4(vals[0], vals[1], vals[2], vals[3]);
    } else {
#pragma unroll
      for (int j = 0; j < 4; j++)
        if (ok[j]) out[basef + j] = vals[j];
    }
  } else {
    // ---- face + uv_idx writer: 1 tet/thread ----
    __shared__ u32 ws[4];
    int tb = bid - nvb - nuvb;
    int t = tb * 256 + tid;
    int code = (t < T) ? (int)tcode[t] : 0;
    int n = c_ntri[code];
    u32 packed = (n == 1 ? 1u : 0u) | (n == 2 ? (1u << 16) : 0u);
    u32 ex = block_exscan_u32(packed, ws, nullptr);
    if (t >= T || n == 0) return;
    u64 bo = boffT[tb];
    u32 s1 = (u32)bo + (ex & 0xffffu);
    u32 s2 = (u32)(bo >> 32) + (ex >> 16);
    u32 E = hdr[0], F1 = hdr[1], F2 = hdr[2];
    u32 F = F1 + 2u * F2;
    size_t fb = (size_t)3 * E;
    size_t ub = fb + (size_t)3 * F + (size_t)8 * NU * NU;
    int c = t / 6, k = t - 6 * c;
    int z = c % R, tq = c / R, y = tq % R, x = tq / R;
    int v000 = (x * R1 + y) * R1 + z;
    int coff[8] = {0, R1sq, R1, R1sq + R1, 1, R1sq + 1, R1 + 1, R1sq + R1 + 1};
    int g4 = 4 * t;
    for (int tri = 0; tri < n; tri++) {
      u32 row = (n == 1) ? s1 : (F1 + 2u * s2 + (u32)tri);
#pragma unroll
      for (int j = 0; j < 3; j++) {
        int slot = c_tt[code][3 * tri + j];
        int ci = c_kuhn[k][c_e0[slot]], cj = c_kuhn[k][c_e1[slot]];
        int oa = coff[ci], ob = coff[cj];
        int lo = oa < ob ? oa : ob;
        int d = oa < ob ? ob - oa : oa - ob;
        int va = v000 + lo;
        int dx = d >= R1sq ? 1 : 0; d -= dx * R1sq;
        int dy = d >= R1 ? 1 : 0;   d -= dy * R1;     // d now dz in {0,1}
        int kb = (dx << 2) + (dy << 1) + d - 1;       // slot in sorted-Delta order
        u32 pv = lpack[va];
        u32 fidx = boffV[va >> 8] + (pv >> 7) + __popc(pv & 0x7fu & ((1u << kb) - 1u));
        out[fb + 3 * row + j] = (float)fidx;
      }
      out[ub + 3 * row + 0] = (float)g4;
      out[ub + 3 * row + 1] = (float)(g4 + tri + 1);
      out[ub + 3 * row + 2] = (float)(g4 + tri + 2);
    }
  }
}

extern "C" void kernel_launch(void* const* d_in, const int* in_sizes, int n_in,
                              void* d_out, int out_size, void* d_ws, size_t ws_size,
                              hipStream_t stream) {
  const float* verts = (const float*)d_in[0];
  const float* sdf = (const float*)d_in[1];
  const float* deform = (const float*)d_in[2];
  int NV = in_sizes[0] / 3;
  int T = in_sizes[3] / 4;
  int R = 1;
  while ((long long)(R + 1) * (R + 1) * (R + 1) < (long long)NV) R++;
  int NU = 1;
  while ((long long)NU * NU < (long long)T) NU++;   // N = ceil(sqrt((2T+1)//2)) = ceil(sqrt(T))
  int nvb = (NV + 255) / 256;                       // vertex blocks
  int ntb = (T + 255) / 256;                        // tet blocks
  long long nchunks = (8LL * NU * NU) / 4 + 2;      // float4 chunks incl. alignment slop
  int nuvb = (int)((nchunks + 255) / 256);          // uv blocks

  // workspace carve (u64 first for alignment); ~2.8 MB total
  char* w = (char*)d_ws;
  u64* boffT = (u64*)w; w += (size_t)ntb * 8;
  u32* bsumV = (u32*)w; w += (size_t)nvb * 4;
  u32* boffV = (u32*)w; w += (size_t)nvb * 4;
  u32* bsumT = (u32*)w; w += (size_t)ntb * 4;
  u32* lpack = (u32*)w; w += (size_t)nvb * 256 * 4;
  u32* hdr = (u32*)w;   w += 64;
  u8* tcode = (u8*)w;   w += (size_t)T;

  float sdefs = 2.0f / (float)(R * 2);  // 1/64 exact
  double inv = 1.0 / (double)NU;
  float* outf = (float*)d_out;

  if (R == 64) {
    kA<64><<<dim3(nvb + ntb), dim3(256), 0, stream>>>(sdf, lpack, tcode, bsumV, bsumT, NV, T, nvb, R);
    kC<<<dim3(2), dim3(1024), 0, stream>>>(bsumV, boffV, nvb, bsumT, boffT, ntb, hdr);
    kD<64, 1255><<<dim3(nvb + nuvb + ntb), dim3(256), 0, stream>>>(
        verts, sdf, deform, lpack, boffV, tcode, boffT, hdr, outf,
        NV, T, nvb, nuvb, R, NU, sdefs, inv);
  } else {
    kA<0><<<dim3(nvb + ntb), dim3(256), 0, stream>>>(sdf, lpack, tcode, bsumV, bsumT, NV, T, nvb, R);
    kC<<<dim3(2), dim3(1024), 0, stream>>>(bsumV, boffV, nvb, bsumT, boffT, ntb, hdr);
    kD<0, 0><<<dim3(nvb + nuvb + ntb), dim3(256), 0, stream>>>(
        verts, sdf, deform, lpack, boffV, tcode, boffT, hdr, outf,
        NV, T, nvb, nuvb, R, NU, sdefs, inv);
  }
}